// Round 5
// baseline (600.918 us; speedup 1.0000x reference)
//
#include <hip/hip_runtime.h>
#include <hip/hip_bf16.h>
#include <stdint.h>

// Problem constants
#define B_N   2048
#define XW    128      // x row width (real 64 | meta 64)
#define KDIM  512      // W_out column count (= H)
#define NROWS_W   66112
#define NROWS_PAD 66560   // padded bf16-W rows

typedef __bf16 v8bf  __attribute__((ext_vector_type(8)));
typedef float  f32x4 __attribute__((ext_vector_type(4)));

__device__ __forceinline__ unsigned short f2bf(float f) {
    uint32_t u = __float_as_uint(f);
    u += 0x7FFF + ((u >> 16) & 1);          // round-to-nearest-even
    return (unsigned short)(u >> 16);
}
__device__ __forceinline__ float elu1(float v) {
    return v > 0.0f ? v : expm1f(v);
}
__device__ __forceinline__ void gload_lds16(const void* g, void* l) {
    __builtin_amdgcn_global_load_lds(
        (const __attribute__((address_space(1))) unsigned int*)g,
        (__attribute__((address_space(3))) unsigned int*)l, 16, 0, 0);
}

// ---------------- K1: h = elu(meta @ W_in^T + b_in), stored bf16 ----------------
__global__ void k_h(const float* __restrict__ x, const float* __restrict__ W_in,
                    const float* __restrict__ b_in, unsigned short* __restrict__ hb) {
    int idx = blockIdx.x * 256 + threadIdx.x;      // b*512 + j
    int b = idx >> 9, j = idx & 511;
    const float4* xm = (const float4*)(x + (size_t)b * XW + 64);
    const float4* wr = (const float4*)(W_in + (size_t)j * 64);
    float acc = 0.f;
#pragma unroll
    for (int q = 0; q < 16; ++q) {
        float4 a = xm[q], w = wr[q];
        acc += a.x * w.x + a.y * w.y + a.z * w.z + a.w * w.w;
    }
    acc = elu1(acc + b_in[j]);
    hb[idx] = f2bf(acc);
}

// ---------------- K-conv: W_out f32 -> bf16 (padded rows zeroed) ---------------
__global__ void k_conv(const float* __restrict__ Wf, unsigned short* __restrict__ Wb) {
    size_t c = (size_t)blockIdx.x * 256 + threadIdx.x;  // 8-elem chunk id
    size_t row = c >> 6; int kk = (int)(c & 63);
    union { uint4 v; unsigned short u[8]; } o;
    o.v = (uint4){0, 0, 0, 0};
    if (row < NROWS_W) {
        const float* wp = Wf + row * KDIM + kk * 8;
        float4 w0 = *(const float4*)wp, w1 = *(const float4*)(wp + 4);
        o.u[0] = f2bf(w0.x); o.u[1] = f2bf(w0.y); o.u[2] = f2bf(w0.z); o.u[3] = f2bf(w0.w);
        o.u[4] = f2bf(w1.x); o.u[5] = f2bf(w1.y); o.u[6] = f2bf(w1.z); o.u[7] = f2bf(w1.w);
    }
    *(uint4*)(Wb + c * 8) = o.v;
}

// ---------------- K-init-ypre: ypre = b_out[32768+hh] + sum_i real_i*b_out[i*512+hh]
__global__ void k_init_ypre(const float* __restrict__ x, const float* __restrict__ b_out,
                            float* __restrict__ ypre) {
    int idx = blockIdx.x * 256 + threadIdx.x;   // b*512 + hh
    int b = idx >> 9, hh = idx & 511;
    float acc = b_out[32768 + hh];
    const float* xr = x + (size_t)b * XW;       // real part
#pragma unroll 8
    for (int i = 0; i < 64; ++i)
        acc += xr[i] * b_out[i * 512 + hh];
    ypre[idx] = acc;
}

// ---------------- K-y: yv = elu(ypre)  (elu computed ONCE per element) ---------
__global__ void k_y(const float* __restrict__ ypre, float* __restrict__ yv) {
    int idx = blockIdx.x * 256 + threadIdx.x;
    yv[idx] = elu1(ypre[idx]);
}

// ---------------- K-init-out: out = b_out[66048+o] + sum_hh yv*b_out[33280+hh*64+o]
__global__ void k_init_out(const float* __restrict__ yv, const float* __restrict__ b_out,
                           float* __restrict__ out) {
    int idx = blockIdx.x * 256 + threadIdx.x;   // b*64 + o
    int b = idx >> 6, o = idx & 63;
    float acc = b_out[66048 + o];
    const float* yr = yv + (size_t)b * 512;
#pragma unroll 4
    for (int hh = 0; hh < 512; ++hh)
        acc += yr[hh] * b_out[33280 + hh * 64 + o];
    out[idx] = acc;
}

// ---------------- panel GEMM: A-in-registers, 4-ring deep pipeline -------------
// P[b,c] = sum_k h[b,k] * W[panelrow(p)+c, k]   (bf16 MFMA, K-quarters of 128)
// outAcc[b, outcol] += s(b, grp) * P            (f32 epilogue per (p,kq))
// Block: 256 rows x 128 panel-cols, 512 thr (8 waves 4x2, wave-tile 64x64).
// A (=h) fragments in registers per kq. B: 4-slot LDS ring, stage t+3 at phase t,
// steady-state s_waitcnt vmcnt(4) -> ~3 phases of load latency cover.
template<int MODE>
__global__ __launch_bounds__(512, 2)
void k_pgemm(const unsigned short* __restrict__ hb,
             const unsigned short* __restrict__ Wb,
             const float* __restrict__ scaleSrc,
             float* __restrict__ outAcc) {
    constexpr int NP   = MODE ? 129 : 130;
    constexpr int OUTW = MODE ? 64 : 512;
    constexpr int SCW  = MODE ? 18 : 9;

    __shared__ char smem[65536 + SCW * 256 * 4];
    char* Bs = smem;                      // 4 x [128][128B], slot ^= row&7
    float* sc = (float*)(smem + 65536);   // [SCW][256]

    // XCD-pinned remap: one split per XCD within each half of the grid.
    const int lid = blockIdx.x;                       // [0,256)
    const int s   = (lid & 7) + 8 * (lid >> 7);       // split id
    const int inner = (lid >> 3) & 15;
    const int m0  = (inner & 7) * 256;
    const int nh  = inner >> 3;

    const int pBeg = (NP * s) >> 4;
    const int pEnd = (NP * (s + 1)) >> 4;
    const int halfS = (MODE == 0 && pBeg >= 65) ? 1 : 0;   // uniform per split
    const int iBeg  = pBeg - halfS * 65;

    const int tid = threadIdx.x;
    const int wid = tid >> 6, l = tid & 63;
    const int lr = l & 15, lg = l >> 4;
    const int wm = wid >> 1, wn = wid & 1;                 // wave grid 4x2

    // ---- stage scales into LDS ----
    for (int c = tid; c < SCW * 256; c += 512) {
        int jj = c >> 8, row = c & 255;
        float v = 1.0f;
        if (MODE == 0) {
            int i = iBeg + jj;
            if (i < 64) v = scaleSrc[(size_t)(m0 + row) * XW + i];
        } else {
            int g = (pBeg + (jj >> 1)) * 4 + nh * 2 + (jj & 1);
            if (g < 512) v = scaleSrc[(size_t)(m0 + row) * KDIM + g];  // yv: already elu'd
        }
        sc[c] = v;
    }
    __syncthreads();

    // ---- per-thread B fragment bases ----
    int bB[4], bX[4];
#pragma unroll
    for (int q = 0; q < 4; ++q) {
        int rb = wn * 64 + q * 16 + lr;
        bB[q] = rb * 128; bX[q] = rb & 7;
    }

    f32x4 accP[4][4], accO[4][4];
#pragma unroll
    for (int mi = 0; mi < 4; ++mi)
#pragma unroll
        for (int ni = 0; ni < 4; ++ni) {
            accP[mi][ni] = (f32x4){0.f, 0.f, 0.f, 0.f};
            accO[mi][ni] = (f32x4){0.f, 0.f, 0.f, 0.f};
        }

    for (int kq = 0; kq < 4; ++kq) {
        // ---- B stage: phase t -> (p = pBeg + (t>>1), k0 = t&1), slot = t&3 ----
        auto stageB = [&](int t) {
            int p = pBeg + (t >> 1), k0c = t & 1;
            int wrow = MODE ? (33280 + p * 256 + nh * 128)
                            : ((p - halfS * 65) * 512 + halfS * 256 + nh * 128);
            const int rsub = tid >> 3;                    // 0..63
            const int sl = (tid & 7) ^ (rsub & 7);        // inverse of read-swizzle
            const unsigned short* src0 = Wb + (size_t)(wrow + rsub) * KDIM
                                       + kq * 128 + k0c * 64 + sl * 8;
            char* dst0 = Bs + (t & 3) * 16384 + tid * 16; // wave-uniform + lane*16
#pragma unroll
            for (int q = 0; q < 2; ++q)
                gload_lds16(src0 + (size_t)q * 64 * KDIM, dst0 + q * 8192);
        };

        // ---- A fragments for this kq -> registers (global, L2-hot) ----
        const unsigned short* abase = hb + (size_t)(m0 + wm * 64 + lr) * KDIM
                                    + kq * 128 + lg * 8;
        v8bf areg[4][4];                                  // [mi][k0*2+ks]
#pragma unroll
        for (int mi = 0; mi < 4; ++mi)
#pragma unroll
            for (int kk2 = 0; kk2 < 4; ++kk2)
                areg[mi][kk2] = *(const v8bf*)(abase + mi * 16 * KDIM + kk2 * 32);

        const int NPH = 2 * (pEnd - pBeg);
        stageB(0); stageB(1); stageB(2);                  // prologue: depth 3

        for (int t = 0; t < NPH; ++t) {
            // wait for slot t (leave up to 2 stages = 4 loads in flight)
            if (t < NPH - 2)      asm volatile("s_waitcnt vmcnt(4)" ::: "memory");
            else if (t == NPH - 2) asm volatile("s_waitcnt vmcnt(2)" ::: "memory");
            else                  asm volatile("s_waitcnt vmcnt(0)" ::: "memory");
            __builtin_amdgcn_s_barrier();                 // barrier #1
            asm volatile("" ::: "memory");
            if (t + 3 < NPH) stageB(t + 3);               // refill ring
            char* Bbuf = Bs + (t & 3) * 16384;
            const int k0 = t & 1;
            __builtin_amdgcn_s_setprio(1);
#pragma unroll
            for (int ks = 0; ks < 2; ++ks) {
                v8bf bfr[4];
                const int sB = ks * 4 + lg;
#pragma unroll
                for (int ni = 0; ni < 4; ++ni)
                    bfr[ni] = *(const v8bf*)(Bbuf + bB[ni] + ((sB ^ bX[ni]) << 4));
#pragma unroll
                for (int mi = 0; mi < 4; ++mi)
#pragma unroll
                    for (int ni = 0; ni < 4; ++ni)
                        accP[mi][ni] = __builtin_amdgcn_mfma_f32_16x16x32_bf16(
                            areg[mi][k0 * 2 + ks], bfr[ni], accP[mi][ni], 0, 0, 0);
            }
            __builtin_amdgcn_s_setprio(0);
            if (k0 == 1) {
                // scale-accumulate P into O (vector f32, broadcast sc reads)
                int pp = t >> 1;
                int jj = MODE ? (pp * 2 + wn) : pp;
                const f32x4* scv = (const f32x4*)(sc + jj * 256);
#pragma unroll
                for (int mi = 0; mi < 4; ++mi) {
                    f32x4 sv = scv[wm * 16 + mi * 4 + lg];
#pragma unroll
                    for (int ni = 0; ni < 4; ++ni) {
                        accO[mi][ni] += sv * accP[mi][ni];
                        accP[mi][ni] = (f32x4){0.f, 0.f, 0.f, 0.f};
                    }
                }
            }
            asm volatile("" ::: "memory");
            __builtin_amdgcn_s_barrier();                 // barrier #2
        }
    }
    // ---- epilogue: atomic accumulate ----
#pragma unroll
    for (int mi = 0; mi < 4; ++mi)
#pragma unroll
        for (int ni = 0; ni < 4; ++ni)
#pragma unroll
            for (int r = 0; r < 4; ++r) {
                int row = wm * 64 + mi * 16 + lg * 4 + r;
                int col = MODE ? (ni * 16 + lr)
                               : (halfS * 256 + nh * 128 + wn * 64 + ni * 16 + lr);
                atomicAdd(outAcc + (size_t)(m0 + row) * OUTW + col, accO[mi][ni][r]);
            }
}

extern "C" void kernel_launch(void* const* d_in, const int* in_sizes, int n_in,
                              void* d_out, int out_size, void* d_ws, size_t ws_size,
                              hipStream_t stream) {
    const float* x     = (const float*)d_in[0];
    const float* W_in  = (const float*)d_in[1];
    const float* b_in  = (const float*)d_in[2];
    const float* W_out = (const float*)d_in[3];
    const float* b_out = (const float*)d_in[4];
    float* out = (float*)d_out;

    char* ws = (char*)d_ws;
    unsigned short* hb = (unsigned short*)ws;            // 2 MB  h bf16
    float* ypre        = (float*)(ws + (2u << 20));      // 4 MB
    float* yv          = (float*)(ws + (6u << 20));      // 4 MB  yv = elu(ypre)
    unsigned short* Wb = (unsigned short*)(ws + (10u << 20));  // 68.2 MB bf16 W_out

    k_h<<<(B_N * 512) / 256, 256, 0, stream>>>(x, W_in, b_in, hb);
    k_conv<<<(NROWS_PAD * KDIM / 8) / 256, 256, 0, stream>>>(W_out, Wb);

    // ypre := bias terms (l_in_b bias + real-weighted l_in_w biases)
    k_init_ypre<<<(B_N * 512) / 256, 256, 0, stream>>>(x, b_out, ypre);

    // Stage 2: ypre += sum_i real_i * (h @ W_i^T)  (+ l_in_b panel, scale 1)
    k_pgemm<0><<<256, 512, 0, stream>>>(hb, Wb, x, ypre);

    // yv := elu(ypre)   (computed once — feeds both k_init_out and pgemm<1> scales)
    k_y<<<(B_N * 512) / 256, 256, 0, stream>>>(ypre, yv);

    // out := bias terms (l_out_b bias + yv-weighted l_out_w biases)
    k_init_out<<<(B_N * 64) / 256, 256, 0, stream>>>(yv, b_out, out);

    // Stage 3: out += sum_h' yv_h' * (h @ W2_h'^T)  (+ l_out_b panel, scale 1)
    k_pgemm<1><<<256, 512, 0, stream>>>(hb, Wb, yv, out);
}

// Round 6
// 292.890 us; speedup vs baseline: 2.0517x; 2.0517x over previous
//
#include <hip/hip_runtime.h>
#include <hip/hip_bf16.h>
#include <stdint.h>

// Problem constants
#define B_N   2048
#define XW    128      // x row width (real 64 | meta 64)
#define KDIM  512      // W_out column count (= H)
#define NROWS_W   66112
#define NROWS_PAD 66560   // padded bf16-W rows

typedef __bf16 v8bf  __attribute__((ext_vector_type(8)));
typedef float  f32x4 __attribute__((ext_vector_type(4)));

__device__ __forceinline__ unsigned short f2bf(float f) {
    uint32_t u = __float_as_uint(f);
    u += 0x7FFF + ((u >> 16) & 1);          // round-to-nearest-even
    return (unsigned short)(u >> 16);
}
__device__ __forceinline__ float elu1(float v) {
    return v > 0.0f ? v : expm1f(v);
}
__device__ __forceinline__ void gload_lds16(const void* g, void* l) {
    __builtin_amdgcn_global_load_lds(
        (const __attribute__((address_space(1))) unsigned int*)g,
        (__attribute__((address_space(3))) unsigned int*)l, 16, 0, 0);
}

// ---------------- K1: h = elu(meta @ W_in^T + b_in), stored bf16 ----------------
__global__ void k_h(const float* __restrict__ x, const float* __restrict__ W_in,
                    const float* __restrict__ b_in, unsigned short* __restrict__ hb) {
    int idx = blockIdx.x * 256 + threadIdx.x;      // b*512 + j
    int b = idx >> 9, j = idx & 511;
    const float4* xm = (const float4*)(x + (size_t)b * XW + 64);
    const float4* wr = (const float4*)(W_in + (size_t)j * 64);
    float acc = 0.f;
#pragma unroll
    for (int q = 0; q < 16; ++q) {
        float4 a = xm[q], w = wr[q];
        acc += a.x * w.x + a.y * w.y + a.z * w.z + a.w * w.w;
    }
    acc = elu1(acc + b_in[j]);
    hb[idx] = f2bf(acc);
}

// ---------------- K-conv: W_out f32 -> bf16 (padded rows zeroed) ---------------
__global__ void k_conv(const float* __restrict__ Wf, unsigned short* __restrict__ Wb) {
    size_t c = (size_t)blockIdx.x * 256 + threadIdx.x;  // 8-elem chunk id
    size_t row = c >> 6; int kk = (int)(c & 63);
    union { uint4 v; unsigned short u[8]; } o;
    o.v = (uint4){0, 0, 0, 0};
    if (row < NROWS_W) {
        const float* wp = Wf + row * KDIM + kk * 8;
        float4 w0 = *(const float4*)wp, w1 = *(const float4*)(wp + 4);
        o.u[0] = f2bf(w0.x); o.u[1] = f2bf(w0.y); o.u[2] = f2bf(w0.z); o.u[3] = f2bf(w0.w);
        o.u[4] = f2bf(w1.x); o.u[5] = f2bf(w1.y); o.u[6] = f2bf(w1.z); o.u[7] = f2bf(w1.w);
    }
    *(uint4*)(Wb + c * 8) = o.v;
}

// ---------------- K-init-ypre: ypre = b_out[32768+hh] + sum_i real_i*b_out[i*512+hh]
__global__ void k_init_ypre(const float* __restrict__ x, const float* __restrict__ b_out,
                            float* __restrict__ ypre) {
    int idx = blockIdx.x * 256 + threadIdx.x;   // b*512 + hh
    int b = idx >> 9, hh = idx & 511;
    float acc = b_out[32768 + hh];
    const float* xr = x + (size_t)b * XW;       // real part
#pragma unroll 8
    for (int i = 0; i < 64; ++i)
        acc += xr[i] * b_out[i * 512 + hh];
    ypre[idx] = acc;
}

// ---------------- K-y: yv = elu(ypre)  (elu computed ONCE per element) ---------
__global__ void k_y(const float* __restrict__ ypre, float* __restrict__ yv) {
    int idx = blockIdx.x * 256 + threadIdx.x;
    yv[idx] = elu1(ypre[idx]);
}

// ---------------- K-init-out: out = b_out[66048+o] + sum_hh yv*b_out[33280+hh*64+o]
__global__ void k_init_out(const float* __restrict__ yv, const float* __restrict__ b_out,
                           float* __restrict__ out) {
    int idx = blockIdx.x * 256 + threadIdx.x;   // b*64 + o
    int b = idx >> 6, o = idx & 63;
    float acc = b_out[66048 + o];
    const float* yr = yv + (size_t)b * 512;
#pragma unroll 4
    for (int hh = 0; hh < 512; ++hh)
        acc += yr[hh] * b_out[33280 + hh * 64 + o];
    out[idx] = acc;
}

// ---------------- panel GEMM: A-in-registers (static idx), 3-ring depth-2 ------
// P[b,c] = sum_k h[b,k] * W[panelrow(p)+c, k]   (bf16 MFMA, K-quarters of 128)
// outAcc[b, outcol] += s(b, grp) * P            (f32 epilogue per panel)
// Block: 128 rows x 128 panel-cols, 256 thr (4 waves 2x2, wave-tile 64x64).
// A (=h) fragments in registers per kq (areg[mi][k0*2+ks], ALL indices static).
// B: 3-slot LDS ring, stage t+2 issued at phase t, steady s_waitcnt vmcnt(8).
template<int MODE>
__global__ __launch_bounds__(256, 2)
void k_pgemm(const unsigned short* __restrict__ hb,
             const unsigned short* __restrict__ Wb,
             const float* __restrict__ scaleSrc,
             float* __restrict__ outAcc) {
    constexpr int NP   = MODE ? 129 : 130;
    constexpr int OUTW = MODE ? 64 : 512;
    constexpr int SCW  = MODE ? 18 : 9;

    __shared__ char smem[3 * 16384 + SCW * 128 * 4];
    char* Bs = smem;                          // 3 x [128 rows][128B], swizzled
    float* sc = (float*)(smem + 3 * 16384);   // [SCW][128]

    // XCD-pinned remap: split s lives entirely on XCD (lid&7); 512 blocks total.
    const int lid = blockIdx.x;                       // [0,512)
    const int s   = (lid & 7) * 2 + (lid >> 8);       // split id 0..15
    const int inner = (lid >> 3) & 31;
    const int m0  = (inner & 15) * 128;
    const int nh  = inner >> 4;

    const int pBeg = (NP * s) >> 4;
    const int pEnd = (NP * (s + 1)) >> 4;
    const int halfS = (MODE == 0 && pBeg >= 65) ? 1 : 0;   // uniform per split
    const int iBeg  = pBeg - halfS * 65;

    const int tid = threadIdx.x;
    const int wid = tid >> 6, l = tid & 63;
    const int lr = l & 15, lg = l >> 4;
    const int wm = wid >> 1, wn = wid & 1;                 // wave grid 2x2

    // ---- stage scales into LDS ----
    for (int c = tid; c < SCW * 128; c += 256) {
        int jj = c >> 7, row = c & 127;
        float v = 1.0f;
        if (MODE == 0) {
            int i = iBeg + jj;
            if (i < 64) v = scaleSrc[(size_t)(m0 + row) * XW + i];
        } else {
            int g = (pBeg + (jj >> 1)) * 4 + nh * 2 + (jj & 1);
            if (g < 512) v = scaleSrc[(size_t)(m0 + row) * KDIM + g];  // yv (elu'd)
        }
        sc[c] = v;
    }
    __syncthreads();

    // ---- per-thread B fragment bases ----
    int bB[4], bX[4];
#pragma unroll
    for (int q = 0; q < 4; ++q) {
        int rb = wn * 64 + q * 16 + lr;
        bB[q] = rb * 128; bX[q] = rb & 7;
    }

    f32x4 accP[4][4], accO[4][4];
#pragma unroll
    for (int mi = 0; mi < 4; ++mi)
#pragma unroll
        for (int ni = 0; ni < 4; ++ni) {
            accP[mi][ni] = (f32x4){0.f, 0.f, 0.f, 0.f};
            accO[mi][ni] = (f32x4){0.f, 0.f, 0.f, 0.f};
        }

    for (int kq = 0; kq < 4; ++kq) {
        // ---- B stage: phase t -> (p = pBeg + (t>>1), k0 = t&1) into ring slot ----
        auto stageB = [&](int slot, int t) {
            int p = pBeg + (t >> 1), k0c = t & 1;
            int wrow = MODE ? (33280 + p * 256 + nh * 128)
                            : ((p - halfS * 65) * 512 + halfS * 256 + nh * 128);
            const int rsub = tid >> 3;                    // 0..31
            const int sl = (tid & 7) ^ (rsub & 7);        // inverse of read-swizzle
            const unsigned short* src0 = Wb + (size_t)(wrow + rsub) * KDIM
                                       + kq * 128 + k0c * 64 + sl * 8;
            char* dst0 = Bs + slot * 16384 + tid * 16;    // wave-uniform + lane*16
#pragma unroll
            for (int q = 0; q < 4; ++q)
                gload_lds16(src0 + (size_t)q * 32 * KDIM, dst0 + q * 4096);
        };

        // ---- A fragments for this kq -> registers (global, L2-hot) ----
        const unsigned short* abase = hb + (size_t)(m0 + wm * 64 + lr) * KDIM
                                    + kq * 128 + lg * 8;
        v8bf areg[4][4];                                  // [mi][k0*2+ks] static only
#pragma unroll
        for (int mi = 0; mi < 4; ++mi)
#pragma unroll
            for (int kk2 = 0; kk2 < 4; ++kk2)
                areg[mi][kk2] = *(const v8bf*)(abase + mi * 16 * KDIM + kk2 * 32);

        const int NPH = 2 * (pEnd - pBeg);                // 16 or 18
        stageB(0, 0);
        stageB(1, 1);
        int slc = 0;                                      // current ring slot

        for (int p = pBeg; p < pEnd; ++p) {
#pragma unroll
            for (int k0 = 0; k0 < 2; ++k0) {              // k0 STATIC (rule #20)
                const int t = (p - pBeg) * 2 + k0;
                int ns = slc + 2; if (ns >= 3) ns -= 3;
                if (t + 2 < NPH) {
                    stageB(ns, t + 2);
                    asm volatile("s_waitcnt vmcnt(8)" ::: "memory");
                } else if (t + 1 < NPH) {
                    asm volatile("s_waitcnt vmcnt(4)" ::: "memory");
                } else {
                    asm volatile("s_waitcnt vmcnt(0)" ::: "memory");
                }
                __builtin_amdgcn_s_barrier();             // barrier #1
                asm volatile("" ::: "memory");
                char* Bbuf = Bs + slc * 16384;
                __builtin_amdgcn_s_setprio(1);
#pragma unroll
                for (int ks = 0; ks < 2; ++ks) {
                    v8bf bfr[4];
                    const int sB = ks * 4 + lg;
#pragma unroll
                    for (int ni = 0; ni < 4; ++ni)
                        bfr[ni] = *(const v8bf*)(Bbuf + bB[ni] + ((sB ^ bX[ni]) << 4));
#pragma unroll
                    for (int mi = 0; mi < 4; ++mi)
#pragma unroll
                        for (int ni = 0; ni < 4; ++ni)
                            accP[mi][ni] = __builtin_amdgcn_mfma_f32_16x16x32_bf16(
                                areg[mi][k0 * 2 + ks], bfr[ni], accP[mi][ni], 0, 0, 0);
                }
                __builtin_amdgcn_s_setprio(0);
                if (k0 == 1) {
                    // scale-accumulate P into O (vector f32, broadcast sc reads)
                    const int pp = p - pBeg;
                    const int jj = MODE ? (pp * 2 + wn) : pp;
                    const f32x4* scv = (const f32x4*)(sc + jj * 128);
#pragma unroll
                    for (int mi = 0; mi < 4; ++mi) {
                        f32x4 sv = scv[wm * 16 + mi * 4 + lg];
#pragma unroll
                        for (int ni = 0; ni < 4; ++ni) {
                            accO[mi][ni] += sv * accP[mi][ni];
                            accP[mi][ni] = (f32x4){0.f, 0.f, 0.f, 0.f};
                        }
                    }
                }
                asm volatile("" ::: "memory");
                __builtin_amdgcn_s_barrier();             // barrier #2
                slc = (slc == 2) ? 0 : slc + 1;
            }
        }
    }
    // ---- epilogue: atomic accumulate ----
#pragma unroll
    for (int mi = 0; mi < 4; ++mi)
#pragma unroll
        for (int ni = 0; ni < 4; ++ni)
#pragma unroll
            for (int r = 0; r < 4; ++r) {
                int row = wm * 64 + mi * 16 + lg * 4 + r;
                int col = MODE ? (ni * 16 + lr)
                               : (halfS * 256 + nh * 128 + wn * 64 + ni * 16 + lr);
                atomicAdd(outAcc + (size_t)(m0 + row) * OUTW + col, accO[mi][ni][r]);
            }
}

extern "C" void kernel_launch(void* const* d_in, const int* in_sizes, int n_in,
                              void* d_out, int out_size, void* d_ws, size_t ws_size,
                              hipStream_t stream) {
    const float* x     = (const float*)d_in[0];
    const float* W_in  = (const float*)d_in[1];
    const float* b_in  = (const float*)d_in[2];
    const float* W_out = (const float*)d_in[3];
    const float* b_out = (const float*)d_in[4];
    float* out = (float*)d_out;

    char* ws = (char*)d_ws;
    unsigned short* hb = (unsigned short*)ws;            // 2 MB  h bf16
    float* ypre        = (float*)(ws + (2u << 20));      // 4 MB
    float* yv          = (float*)(ws + (6u << 20));      // 4 MB  yv = elu(ypre)
    unsigned short* Wb = (unsigned short*)(ws + (10u << 20));  // 68.2 MB bf16 W_out

    k_h<<<(B_N * 512) / 256, 256, 0, stream>>>(x, W_in, b_in, hb);
    k_conv<<<(NROWS_PAD * KDIM / 8) / 256, 256, 0, stream>>>(W_out, Wb);

    // ypre := bias terms (l_in_b bias + real-weighted l_in_w biases)
    k_init_ypre<<<(B_N * 512) / 256, 256, 0, stream>>>(x, b_out, ypre);

    // Stage 2: ypre += sum_i real_i * (h @ W_i^T)  (+ l_in_b panel, scale 1)
    k_pgemm<0><<<512, 256, 0, stream>>>(hb, Wb, x, ypre);

    // yv := elu(ypre)   (computed once — feeds both k_init_out and pgemm<1> scales)
    k_y<<<(B_N * 512) / 256, 256, 0, stream>>>(ypre, yv);

    // out := bias terms (l_out_b bias + yv-weighted l_out_w biases)
    k_init_out<<<(B_N * 64) / 256, 256, 0, stream>>>(yv, b_out, out);

    // Stage 3: out += sum_h' yv_h' * (h @ W2_h'^T)  (+ l_out_b panel, scale 1)
    k_pgemm<1><<<512, 256, 0, stream>>>(hb, Wb, yv, out);
}